// Round 1
// 740.231 us; speedup vs baseline: 1.0594x; 1.0594x over previous
//
#include <hip/hip_runtime.h>
#include <stdint.h>

#define NF    1008
#define NH1   256
#define NH2   192
#define NH3   160
#define MT    64
#define CELU_ALPHA 0.1f

typedef __attribute__((ext_vector_type(8))) __bf16 bf16x8;
typedef __attribute__((ext_vector_type(4))) float  f32x4;

// ws layout (bytes)
// Fragment-major weights: frag(j,ks) = 512 bf16, lane-major [l=0..63][e=0..7]
//   value = W[t][k = ks*32 + (l>>4)*8 + e][n = j*16 + (l&15)]   (zero-padded k)
#define W1F_OFF   0u           // bf16 [5][16][32][512] = 2,621,440
#define W2F_OFF   2621440u     // bf16 [5][12][ 8][512] =   491,520
#define W3F_OFF   3112960u     // bf16 [5][10][ 6][512] =   307,200
#define META_OFF  3420160u     // ints: counts[5]@0, atom_base[6]@8, tile_base[6]@16, cursors[5]@24
#define SORT_OFF  3420288u     // int [100000]

__device__ __forceinline__ unsigned short f2bf(float f) {
  union { float f; uint32_t u; } v; v.f = f;
  uint32_t u = v.u;
  uint32_t r = u + 0x7FFFu + ((u >> 16) & 1u);   // round-to-nearest-even
  return (unsigned short)(r >> 16);
}

__device__ __forceinline__ float celu_f(float x) {
  return x > 0.f ? x : CELU_ALPHA * (__expf(x * (1.f / CELU_ALPHA)) - 1.f);
}

__device__ __forceinline__ int ztype(int z) {
  return z == 1 ? 0 : z == 6 ? 1 : z == 7 ? 2 : z == 8 ? 3 : 4;
}

// ---------------- preprocessing ----------------
// blocks [0,425): convert weights -> bf16 MFMA-fragment-major layout
// blocks [425, 425+nb): per-type histogram of z
__global__ void prep_and_hist(const float* __restrict__ W1, const float* __restrict__ W2,
                              const float* __restrict__ W3,
                              unsigned short* __restrict__ w1f, unsigned short* __restrict__ w2f,
                              unsigned short* __restrict__ w3f,
                              const int* __restrict__ z, int n, int* __restrict__ counts) {
  int bid = blockIdx.x;
  int tid = threadIdx.x;
  if (bid >= 425) {
    __shared__ int h[5];
    if (tid < 5) h[tid] = 0;
    __syncthreads();
    int i = (bid - 425) * 256 + tid;
    if (i < n) atomicAdd(&h[ztype(z[i])], 1);
    __syncthreads();
    if (tid < 5 && h[tid]) atomicAdd(&counts[tid], h[tid]);
    return;
  }
  const float* src; unsigned short* dst; int K, N, NJ, NKS, kt, nt;
  if (bid < 320) {              // W1: 16 k-tiles x 4 n-tiles x 5 types
    int t = bid / 64, r = bid % 64; kt = r / 4; nt = r % 4;
    src = W1 + (size_t)t * NF * NH1; dst = w1f + (size_t)t * 16 * 32 * 512;
    K = NF; N = NH1; NJ = 16; NKS = 32;
  } else if (bid < 380) {       // W2: 4x3 tiles x 5 types
    int b = bid - 320; int t = b / 12, r = b % 12; kt = r / 3; nt = r % 3;
    src = W2 + (size_t)t * NH1 * NH2; dst = w2f + (size_t)t * 12 * 8 * 512;
    K = NH1; N = NH2; NJ = 12; NKS = 8;
  } else {                      // W3: 3x3 tiles x 5 types
    int b = bid - 380; int t = b / 9, r = b % 9; kt = r / 3; nt = r % 3;
    src = W3 + (size_t)t * NH2 * NH3; dst = w3f + (size_t)t * 10 * 6 * 512;
    K = NH2; N = NH3; NJ = 10; NKS = 6;
  }
  __shared__ float tile[64][65];
  int k0 = kt * 64, n0 = nt * 64;
  {
    int nl = tid & 63, kb = tid >> 6;
    #pragma unroll
    for (int i = 0; i < 16; ++i) {
      int kl = kb + 4 * i;
      int k = k0 + kl, nn = n0 + nl;
      tile[kl][nl] = (k < K && nn < N) ? src[(size_t)k * N + nn] : 0.f;
    }
  }
  __syncthreads();
  // write phase: each 64x64 tile covers fragments (j2=0..3, ks2=0..1)
  {
    #pragma unroll
    for (int i = 0; i < 16; ++i) {
      int o = tid + 256 * i;               // 0..4095
      int e  = o & 7;
      int l  = (o >> 3) & 63;
      int ks2 = (o >> 9) & 1;
      int j2  = o >> 10;
      int kl = ks2 * 32 + ((l >> 4) << 3) + e;   // local k
      int nl = j2 * 16 + (l & 15);               // local n
      int gj  = (n0 >> 4) + j2;
      int gks = (k0 >> 5) + ks2;
      if (gj < NJ && gks < NKS)
        dst[((size_t)gj * NKS + gks) * 512 + (o & 511)] = f2bf(tile[kl][nl]);
    }
  }
}

__global__ void plan_tiles(const int* __restrict__ counts, int* __restrict__ atom_base,
                           int* __restrict__ tile_base) {
  if (threadIdx.x == 0 && blockIdx.x == 0) {
    int a = 0, tb = 0;
    for (int t = 0; t < 5; ++t) {
      atom_base[t] = a; tile_base[t] = tb;
      a += counts[t]; tb += (counts[t] + MT - 1) / MT;
    }
    atom_base[5] = a; tile_base[5] = tb;
  }
}

__global__ void scatter_atoms(const int* __restrict__ z, int n,
                              const int* __restrict__ atom_base, int* __restrict__ cursors,
                              int* __restrict__ sorted) {
  int i = blockIdx.x * blockDim.x + threadIdx.x;
  int lane = threadIdx.x & 63;
  int t = (i < n) ? ztype(z[i]) : -1;
  #pragma unroll
  for (int tt = 0; tt < 5; ++tt) {
    unsigned long long mask = __ballot(t == tt);
    if (t == tt) {
      int leader = __ffsll((long long)mask) - 1;
      int rank = __popcll(mask & ((1ull << lane) - 1ull));
      int base = 0;
      if (lane == leader) base = atomicAdd(&cursors[tt], (int)__popcll(mask));
      base = __shfl(base, leader);
      sorted[atom_base[tt] + base + rank] = i;
    }
  }
}

// ---------------- fused MLP ----------------
// One block = 64 atoms of one type, 8 waves (512 thr). Wave w owns n-tiles j = w + 8*jj.
// LDS 65,792 B -> 2 blocks/CU. All tiles XOR-swizzled: elem ^= (row&7)<<3
//   A dbuf: A0 [0,32768)B + A1 [32768,65536)B, each 64 x 256 bf16
//   h1 [0,32768)B stride 256  (overlaps A0; dead after L1 K-loop)
//   h2 [32768,57344)B stride 192 (overlaps A1; dead after L1)
//   h3 [0,24576)B stride 192  (overlaps h1; h1 dead after L2 MFMAs + barrier)
//   lgid @ 65536
__global__ __launch_bounds__(512, 4) void fcnn_main(
    const float* __restrict__ feat, const int* __restrict__ batch,
    const unsigned short* __restrict__ w1f, const unsigned short* __restrict__ w2f,
    const unsigned short* __restrict__ w3f, const float* __restrict__ W4,
    const float* __restrict__ b1, const float* __restrict__ b2,
    const float* __restrict__ b3, const float* __restrict__ b4,
    const int* __restrict__ atom_base, const int* __restrict__ tile_base,
    const int* __restrict__ sorted_idx, float* __restrict__ out) {
  __shared__ __align__(16) unsigned char smem[65792];
  unsigned short* A0  = (unsigned short*)smem;                 // elems [0,16384)
  unsigned short* A1  = (unsigned short*)(smem + 32768);       // elems [0,16384)
  unsigned short* h1s = (unsigned short*)smem;                 // 64 x 256
  unsigned short* h2s = (unsigned short*)(smem + 32768);       // 64 x 192
  unsigned short* h3s = (unsigned short*)smem;                 // 64 x 192
  int* lgid = (int*)(smem + 65536);

  const int bid = blockIdx.x;
  if (bid >= tile_base[5]) return;
  int t = 0;
  #pragma unroll
  for (int i = 0; i < 4; ++i) if (bid >= tile_base[i + 1]) t = i + 1;
  const int m0 = atom_base[t] + (bid - tile_base[t]) * MT;
  const int rows = min(MT, atom_base[t + 1] - m0);

  const int tid = threadIdx.x;
  const int lane = tid & 63;
  const int w = tid >> 6;          // 0..7
  const int col = lane & 15;
  const int q = lane >> 4;
  const int lx8 = lane << 3;       // lane*8 elems: fragment lane offset
  const int swzR = (col & 7) << 3; // read-side XOR (row&7 == col&7 for af reads)

  if (tid < MT) lgid[tid] = (tid < rows) ? sorted_idx[m0 + tid] : -1;
  __syncthreads();

  // ---- Layer 1: h1[64,256] = celu(A[64,1008] x W1 + b1), 4 K-chunks of 256
  const int srow = tid >> 3;       // 0..63
  const int sl = tid & 7;
  const int sg = lgid[srow];
  const float* fsrc = (sg >= 0) ? (feat + (size_t)sg * NF) : feat;
  const int swzW = (srow & 7) << 3;

  const unsigned short* w1p0 = w1f + (size_t)t * 16 * 32 * 512 + (size_t)w * 32 * 512 + lx8;
  const unsigned short* w1p1 = w1p0 + 8 * 32 * 512;

  f32x4 acc[4][2];
  #pragma unroll
  for (int a = 0; a < 4; ++a)
    #pragma unroll
    for (int b = 0; b < 2; ++b) acc[a][b] = (f32x4){0.f, 0.f, 0.f, 0.f};

  f32x4 nv[8];
  #pragma unroll
  for (int i = 0; i < 8; ++i) {
    int k = (sl + 8 * i) * 4;
    nv[i] = (sg >= 0 && k < NF) ? *(const f32x4*)(fsrc + k) : (f32x4){0.f, 0.f, 0.f, 0.f};
  }
  #pragma unroll
  for (int i = 0; i < 8; ++i) {
    int c = sl + 8 * i;
    ushort4 pk;
    pk.x = f2bf(nv[i][0]); pk.y = f2bf(nv[i][1]); pk.z = f2bf(nv[i][2]); pk.w = f2bf(nv[i][3]);
    *(ushort4*)(A0 + srow * 256 + (((c << 2)) ^ swzW)) = pk;
  }
  __syncthreads();

  #pragma unroll 1
  for (int kc = 0; kc < 4; ++kc) {
    if (kc < 3) {
      #pragma unroll
      for (int i = 0; i < 8; ++i) {
        int k = (kc + 1) * 256 + (sl + 8 * i) * 4;
        nv[i] = (sg >= 0 && k < NF) ? *(const f32x4*)(fsrc + k) : (f32x4){0.f, 0.f, 0.f, 0.f};
      }
    }
    const unsigned short* ab = (kc & 1) ? A1 : A0;
    #pragma unroll
    for (int ks = 0; ks < 8; ++ks) {
      bf16x8 af[4];
      #pragma unroll
      for (int im = 0; im < 4; ++im)
        af[im] = *(const bf16x8*)(ab + (im * 16 + col) * 256 + ((ks * 32 + q * 8) ^ swzR));
      bf16x8 bf0 = *(const bf16x8*)(w1p0 + (size_t)(kc * 8 + ks) * 512);
      bf16x8 bf1 = *(const bf16x8*)(w1p1 + (size_t)(kc * 8 + ks) * 512);
      #pragma unroll
      for (int im = 0; im < 4; ++im) {
        acc[im][0] = __builtin_amdgcn_mfma_f32_16x16x32_bf16(af[im], bf0, acc[im][0], 0, 0, 0);
        acc[im][1] = __builtin_amdgcn_mfma_f32_16x16x32_bf16(af[im], bf1, acc[im][1], 0, 0, 0);
      }
    }
    if (kc < 3) {
      unsigned short* dst = (kc & 1) ? A0 : A1;   // buffer (kc+1)&1
      #pragma unroll
      for (int i = 0; i < 8; ++i) {
        int c = sl + 8 * i;
        ushort4 pk;
        pk.x = f2bf(nv[i][0]); pk.y = f2bf(nv[i][1]); pk.z = f2bf(nv[i][2]); pk.w = f2bf(nv[i][3]);
        *(ushort4*)(dst + srow * 256 + (((c << 2)) ^ swzW)) = pk;
      }
    }
    __syncthreads();
  }

  // epilogue L1 -> h1 (stride 256, swizzled, overlaps dead A0)
  #pragma unroll
  for (int jj = 0; jj < 2; ++jj) {
    int n = (w + 8 * jj) * 16 + col;
    float bias = b1[t * NH1 + n];
    #pragma unroll
    for (int im = 0; im < 4; ++im)
      #pragma unroll
      for (int r = 0; r < 4; ++r) {
        int row = im * 16 + q * 4 + r;
        h1s[row * 256 + (n ^ ((row & 7) << 3))] = f2bf(celu_f(acc[im][jj][r] + bias));
      }
  }
  __syncthreads();

  // ---- Layer 2: h2[64,192] = celu(h1 x W2 + b2), K=256, 12 n-tiles
  f32x4 acc2[4][2];
  #pragma unroll
  for (int a = 0; a < 4; ++a)
    #pragma unroll
    for (int b = 0; b < 2; ++b) acc2[a][b] = (f32x4){0.f, 0.f, 0.f, 0.f};
  const unsigned short* w2p0 = w2f + (size_t)t * 12 * 8 * 512 + (size_t)w * 8 * 512 + lx8;
  const unsigned short* w2p1 = w2p0 + 8 * 8 * 512;   // j = w+8, valid iff w < 4
  #pragma unroll
  for (int ks = 0; ks < 8; ++ks) {
    bf16x8 af[4];
    #pragma unroll
    for (int im = 0; im < 4; ++im)
      af[im] = *(const bf16x8*)(h1s + (im * 16 + col) * 256 + ((ks * 32 + q * 8) ^ swzR));
    bf16x8 bf0 = *(const bf16x8*)(w2p0 + (size_t)ks * 512);
    #pragma unroll
    for (int im = 0; im < 4; ++im)
      acc2[im][0] = __builtin_amdgcn_mfma_f32_16x16x32_bf16(af[im], bf0, acc2[im][0], 0, 0, 0);
    if (w < 4) {
      bf16x8 bf1 = *(const bf16x8*)(w2p1 + (size_t)ks * 512);
      #pragma unroll
      for (int im = 0; im < 4; ++im)
        acc2[im][1] = __builtin_amdgcn_mfma_f32_16x16x32_bf16(af[im], bf1, acc2[im][1], 0, 0, 0);
    }
  }
  #pragma unroll
  for (int jj = 0; jj < 2; ++jj) {
    int j = w + 8 * jj;
    if (j < 12) {
      int n = j * 16 + col;
      float bias = b2[t * NH2 + n];
      #pragma unroll
      for (int im = 0; im < 4; ++im)
        #pragma unroll
        for (int r = 0; r < 4; ++r) {
          int row = im * 16 + q * 4 + r;
          h2s[row * 192 + (n ^ ((row & 7) << 3))] = f2bf(celu_f(acc2[im][jj][r] + bias));
        }
    }
  }
  __syncthreads();

  // ---- Layer 3: h3[64,160] = celu(h2 x W3 + b3), K=192, 10 n-tiles
  f32x4 acc3[4][2];
  #pragma unroll
  for (int a = 0; a < 4; ++a)
    #pragma unroll
    for (int b = 0; b < 2; ++b) acc3[a][b] = (f32x4){0.f, 0.f, 0.f, 0.f};
  const unsigned short* w3p0 = w3f + (size_t)t * 10 * 6 * 512 + (size_t)w * 6 * 512 + lx8;
  const unsigned short* w3p1 = w3p0 + 8 * 6 * 512;   // j = w+8, valid iff w < 2
  #pragma unroll
  for (int ks = 0; ks < 6; ++ks) {
    bf16x8 af[4];
    #pragma unroll
    for (int im = 0; im < 4; ++im)
      af[im] = *(const bf16x8*)(h2s + (im * 16 + col) * 192 + ((ks * 32 + q * 8) ^ swzR));
    bf16x8 bf0 = *(const bf16x8*)(w3p0 + (size_t)ks * 512);
    #pragma unroll
    for (int im = 0; im < 4; ++im)
      acc3[im][0] = __builtin_amdgcn_mfma_f32_16x16x32_bf16(af[im], bf0, acc3[im][0], 0, 0, 0);
    if (w < 2) {
      bf16x8 bf1 = *(const bf16x8*)(w3p1 + (size_t)ks * 512);
      #pragma unroll
      for (int im = 0; im < 4; ++im)
        acc3[im][1] = __builtin_amdgcn_mfma_f32_16x16x32_bf16(af[im], bf1, acc3[im][1], 0, 0, 0);
    }
  }
  #pragma unroll
  for (int jj = 0; jj < 2; ++jj) {
    int j = w + 8 * jj;
    if (j < 10) {
      int n = j * 16 + col;
      float bias = b3[t * NH3 + n];
      #pragma unroll
      for (int im = 0; im < 4; ++im)
        #pragma unroll
        for (int r = 0; r < 4; ++r) {
          int row = im * 16 + q * 4 + r;
          h3s[row * 192 + (n ^ ((row & 7) << 3))] = f2bf(celu_f(acc3[im][jj][r] + bias));
        }
    }
  }
  __syncthreads();

  // ---- Layer 4: v = h3 . W4[t] + b4[t]; atomicAdd into molecule
  {
    int a = tid >> 3, p = tid & 7;
    float v = 0.f;
    if (a < rows) {
      const float* wp = W4 + t * NH3;
      int aswz = (a & 7) << 3;
      #pragma unroll
      for (int c0 = 0; c0 < 3; ++c0) {
        int c = p + 8 * c0;   // 20 chunks of 8 elems
        if (c < 20) {
          bf16x8 hv = *(const bf16x8*)(h3s + a * 192 + ((c * 8) ^ aswz));
          #pragma unroll
          for (int j = 0; j < 8; ++j) v += (float)hv[j] * wp[c * 8 + j];
        }
      }
    }
    v += __shfl_xor(v, 1);
    v += __shfl_xor(v, 2);
    v += __shfl_xor(v, 4);
    if (p == 0 && a < rows) {
      int g = lgid[a];
      atomicAdd(&out[batch[g]], v + b4[t]);
    }
  }
}

// ---------------- launch ----------------
extern "C" void kernel_launch(void* const* d_in, const int* in_sizes, int n_in,
                              void* d_out, int out_size, void* d_ws, size_t ws_size,
                              hipStream_t stream) {
  const int*   z    = (const int*)d_in[0];
  const float* feat = (const float*)d_in[1];
  const int*   bat  = (const int*)d_in[2];
  const float* W1 = (const float*)d_in[4];
  const float* b1 = (const float*)d_in[5];
  const float* W2 = (const float*)d_in[6];
  const float* b2 = (const float*)d_in[7];
  const float* W3 = (const float*)d_in[8];
  const float* b3 = (const float*)d_in[9];
  const float* W4 = (const float*)d_in[10];
  const float* b4 = (const float*)d_in[11];
  const int n = in_sizes[0];

  unsigned char* ws = (unsigned char*)d_ws;
  unsigned short* w1f = (unsigned short*)(ws + W1F_OFF);
  unsigned short* w2f = (unsigned short*)(ws + W2F_OFF);
  unsigned short* w3f = (unsigned short*)(ws + W3F_OFF);
  int* meta = (int*)(ws + META_OFF);
  int* counts    = meta;
  int* atom_base = meta + 8;
  int* tile_base = meta + 16;
  int* cursors   = meta + 24;
  int* sorted    = (int*)(ws + SORT_OFF);

  hipMemsetAsync(meta, 0, 128, stream);
  hipMemsetAsync(d_out, 0, (size_t)out_size * sizeof(float), stream);

  int nb = (n + 255) / 256;
  prep_and_hist<<<425 + nb, 256, 0, stream>>>(W1, W2, W3, w1f, w2f, w3f, z, n, counts);
  plan_tiles<<<1, 64, 0, stream>>>(counts, atom_base, tile_base);
  scatter_atoms<<<nb, 256, 0, stream>>>(z, n, atom_base, cursors, sorted);
  int max_tiles = n / MT + 6;
  fcnn_main<<<max_tiles, 512, 0, stream>>>(feat, bat, w1f, w2f, w3f, W4,
                                           b1, b2, b3, b4,
                                           atom_base, tile_base, sorted,
                                           (float*)d_out);
  (void)n_in; (void)ws_size;
}

// Round 2
// 711.024 us; speedup vs baseline: 1.1029x; 1.0411x over previous
//
#include <hip/hip_runtime.h>
#include <stdint.h>

#define NF    1008
#define NH1   256
#define NH2   192
#define NH3   160
#define MT    64
#define CELU_ALPHA 0.1f

typedef __attribute__((ext_vector_type(8))) __bf16 bf16x8;
typedef __attribute__((ext_vector_type(4))) __bf16 bf16x4;
typedef __attribute__((ext_vector_type(4))) float  f32x4;

// ws layout (bytes)
// Fragment-major weights: frag(j,ks) = 512 bf16, lane-major [l=0..63][e=0..7]
//   value = W[t][k = ks*32 + (l>>4)*8 + e][n = j*16 + (l&15)]   (zero-padded k)
#define W1F_OFF   0u           // bf16 [5][16][32][512] = 2,621,440
#define W2F_OFF   2621440u     // bf16 [5][12][ 8][512] =   491,520
#define W3F_OFF   3112960u     // bf16 [5][10][ 6][512] =   307,200
#define META_OFF  3420160u     // ints: counts[5]@0, cursors[5]@24
#define SORT_OFF  3420288u     // int [100000]

__device__ __forceinline__ unsigned short f2bf(float f) {
  union { float f; uint32_t u; } v; v.f = f;
  uint32_t u = v.u;
  uint32_t r = u + 0x7FFFu + ((u >> 16) & 1u);   // round-to-nearest-even
  return (unsigned short)(r >> 16);
}

__device__ __forceinline__ float celu_f(float x) {
  return x > 0.f ? x : CELU_ALPHA * (__expf(x * (1.f / CELU_ALPHA)) - 1.f);
}

__device__ __forceinline__ int ztype(int z) {
  return z == 1 ? 0 : z == 6 ? 1 : z == 7 ? 2 : z == 8 ? 3 : 4;
}

// ---------------- preprocessing ----------------
// blocks [0,425): convert weights -> bf16 MFMA-fragment-major layout
// blocks [425, 425+nb): per-type histogram of z
__global__ void prep_and_hist(const float* __restrict__ W1, const float* __restrict__ W2,
                              const float* __restrict__ W3,
                              unsigned short* __restrict__ w1f, unsigned short* __restrict__ w2f,
                              unsigned short* __restrict__ w3f,
                              const int* __restrict__ z, int n, int* __restrict__ counts) {
  int bid = blockIdx.x;
  int tid = threadIdx.x;
  if (bid >= 425) {
    __shared__ int h[5];
    if (tid < 5) h[tid] = 0;
    __syncthreads();
    int i = (bid - 425) * 256 + tid;
    if (i < n) atomicAdd(&h[ztype(z[i])], 1);
    __syncthreads();
    if (tid < 5 && h[tid]) atomicAdd(&counts[tid], h[tid]);
    return;
  }
  const float* src; unsigned short* dst; int K, N, NJ, NKS, kt, nt;
  if (bid < 320) {              // W1: 16 k-tiles x 4 n-tiles x 5 types
    int t = bid / 64, r = bid % 64; kt = r / 4; nt = r % 4;
    src = W1 + (size_t)t * NF * NH1; dst = w1f + (size_t)t * 16 * 32 * 512;
    K = NF; N = NH1; NJ = 16; NKS = 32;
  } else if (bid < 380) {       // W2: 4x3 tiles x 5 types
    int b = bid - 320; int t = b / 12, r = b % 12; kt = r / 3; nt = r % 3;
    src = W2 + (size_t)t * NH1 * NH2; dst = w2f + (size_t)t * 12 * 8 * 512;
    K = NH1; N = NH2; NJ = 12; NKS = 8;
  } else {                      // W3: 3x3 tiles x 5 types
    int b = bid - 380; int t = b / 9, r = b % 9; kt = r / 3; nt = r % 3;
    src = W3 + (size_t)t * NH2 * NH3; dst = w3f + (size_t)t * 10 * 6 * 512;
    K = NH2; N = NH3; NJ = 10; NKS = 6;
  }
  __shared__ float tile[64][65];
  int k0 = kt * 64, n0 = nt * 64;
  {
    int nl = tid & 63, kb = tid >> 6;
    #pragma unroll
    for (int i = 0; i < 16; ++i) {
      int kl = kb + 4 * i;
      int k = k0 + kl, nn = n0 + nl;
      tile[kl][nl] = (k < K && nn < N) ? src[(size_t)k * N + nn] : 0.f;
    }
  }
  __syncthreads();
  // write phase: each 64x64 tile covers fragments (j2=0..3, ks2=0..1)
  {
    #pragma unroll
    for (int i = 0; i < 16; ++i) {
      int o = tid + 256 * i;               // 0..4095
      int e  = o & 7;
      int l  = (o >> 3) & 63;
      int ks2 = (o >> 9) & 1;
      int j2  = o >> 10;
      int kl = ks2 * 32 + ((l >> 4) << 3) + e;   // local k
      int nl = j2 * 16 + (l & 15);               // local n
      int gj  = (n0 >> 4) + j2;
      int gks = (k0 >> 5) + ks2;
      if (gj < NJ && gks < NKS)
        dst[((size_t)gj * NKS + gks) * 512 + (o & 511)] = f2bf(tile[kl][nl]);
    }
  }
}

__global__ void scatter_atoms(const int* __restrict__ z, int n,
                              const int* __restrict__ counts, int* __restrict__ cursors,
                              int* __restrict__ sorted) {
  int i = blockIdx.x * blockDim.x + threadIdx.x;
  int lane = threadIdx.x & 63;
  int t = (i < n) ? ztype(z[i]) : -1;
  int ab = 0;
  #pragma unroll
  for (int tt = 0; tt < 5; ++tt) {
    unsigned long long mask = __ballot(t == tt);
    if (t == tt) {
      int leader = __ffsll((long long)mask) - 1;
      int rank = __popcll(mask & ((1ull << lane) - 1ull));
      int base = 0;
      if (lane == leader) base = atomicAdd(&cursors[tt], (int)__popcll(mask));
      base = __shfl(base, leader);
      sorted[ab + base + rank] = i;
    }
    ab += counts[tt];
  }
}

// ---------------- fused MLP ----------------
// One block = 64 atoms of one type, 8 waves (512 thr). Wave w owns n-tiles j = w (+8).
// L1 restructured: KC=128, weights-in-registers per chunk, vmcnt-clean issue order:
//   per chunk: [MFMA (reg weights, no slow loads ahead)] -> [pack feat] ->
//              [issue next-chunk weights] -> barrier -> [issue next feat]
// LDS 57,600 B -> 2 blocks/CU. Tiles XOR-swizzled: elem ^= (row&7)<<3
//   A dbuf: A0 [0,16K)B + A1 [16K,32K)B, each 64 x 128 bf16
//   h1 [0,32K)B stride 256   (overlaps A dbuf; dead after L1 K-loop)
//   h2 [32K,56K)B stride 192
//   h3 [0,24K)B stride 192   (overlaps h1; h1 dead after L2 MFMAs + barrier)
//   lgid @ 57344
__global__ __launch_bounds__(512, 4) void fcnn_main(
    const float* __restrict__ feat, const int* __restrict__ batch,
    const unsigned short* __restrict__ w1f, const unsigned short* __restrict__ w2f,
    const unsigned short* __restrict__ w3f, const float* __restrict__ W4,
    const float* __restrict__ b1, const float* __restrict__ b2,
    const float* __restrict__ b3, const float* __restrict__ b4,
    const int* __restrict__ counts, const int* __restrict__ sorted_idx,
    float* __restrict__ out) {
  __shared__ __align__(16) unsigned char smem[57600];
  __bf16* A0v = (__bf16*)smem;                 // 64 x 128
  __bf16* A1v = (__bf16*)(smem + 16384);       // 64 x 128
  __bf16* h1s = (__bf16*)smem;                 // 64 x 256
  __bf16* h2s = (__bf16*)(smem + 32768);       // 64 x 192
  __bf16* h3s = (__bf16*)smem;                 // 64 x 192
  int* lgid = (int*)(smem + 57344);

  const int bid = blockIdx.x;
  // block -> (t, m0, rows) from counts (plan_tiles fused away)
  int t = 0, abase = 0, tbase = 0, cend = 0, total_t = 0, total_a = 0;
  #pragma unroll
  for (int i = 0; i < 5; ++i) {
    int ci = counts[i];
    int nti = (ci + MT - 1) / MT;
    if (bid >= total_t && bid < total_t + nti) { t = i; abase = total_a; tbase = total_t; cend = total_a + ci; }
    total_t += nti; total_a += ci;
  }
  if (bid >= total_t) return;
  const int m0 = abase + (bid - tbase) * MT;
  const int rows = min(MT, cend - m0);

  const int tid = threadIdx.x;
  const int lane = tid & 63;
  const int w = tid >> 6;          // 0..7
  const int col = lane & 15;
  const int q = lane >> 4;
  const int lx8 = lane << 3;       // lane*8 elems: fragment lane offset
  const int swzR = (col & 7) << 3; // read-side XOR (row&7 == col&7 for af reads)

  // ---- Layer 1: h1[64,256] = celu(A[64,1008] x W1 + b1), 8 K-chunks of 128
  const int srow = tid >> 3;       // 0..63
  const int sl = tid & 7;
  const int sg = (srow < rows) ? sorted_idx[m0 + srow] : -1;
  if (tid < MT) lgid[tid] = (tid < rows) ? sorted_idx[m0 + tid] : -1;
  const float* fsrc = (sg >= 0) ? (feat + (size_t)sg * NF) : feat;
  const int swzW = (srow & 7) << 3;

  const unsigned short* w1p0 = w1f + (size_t)t * 16 * 32 * 512 + (size_t)w * 32 * 512 + lx8;
  const unsigned short* w1p1 = w1p0 + 8 * 32 * 512;

  f32x4 acc[4][2];
  #pragma unroll
  for (int a = 0; a < 4; ++a)
    #pragma unroll
    for (int b = 0; b < 2; ++b) acc[a][b] = (f32x4){0.f, 0.f, 0.f, 0.f};

  f32x4 nv[4];
  bf16x8 wf[8];   // [0..3]=j0 ks0..3, [4..7]=j1 ks0..3 for current chunk

  auto feat_issue = [&](int kc1) {
    #pragma unroll
    for (int i = 0; i < 4; ++i) {
      int k = kc1 * 128 + ((sl + 8 * i) << 2);
      nv[i] = (sg >= 0 && k < NF) ? *(const f32x4*)(fsrc + k) : (f32x4){0.f, 0.f, 0.f, 0.f};
    }
  };
  auto pack_to = [&](__bf16* dstp) {
    #pragma unroll
    for (int i = 0; i < 4; ++i) {
      int c4 = (sl + 8 * i) << 2;
      bf16x4 pk = { (__bf16)nv[i][0], (__bf16)nv[i][1], (__bf16)nv[i][2], (__bf16)nv[i][3] };
      *(bf16x4*)(dstp + srow * 128 + (c4 ^ swzW)) = pk;
    }
  };
  auto wf_issue = [&](int kc1) {
    #pragma unroll
    for (int ks = 0; ks < 4; ++ks) {
      wf[ks]     = *(const bf16x8*)(w1p0 + (size_t)(kc1 * 4 + ks) * 512);
      wf[4 + ks] = *(const bf16x8*)(w1p1 + (size_t)(kc1 * 4 + ks) * 512);
    }
  };

  // prologue: chunk 0 staged; weights for chunk 0 issued after the feat drain
  feat_issue(0);
  pack_to(A0v);
  wf_issue(0);
  __syncthreads();

  #pragma unroll 1
  for (int kc = 0; kc < 8; ++kc) {
    const __bf16* ab = (kc & 1) ? A1v : A0v;
    if (kc < 7) feat_issue(kc + 1);          // slow loads issued AFTER current weights retired
    __builtin_amdgcn_s_setprio(1);
    #pragma unroll
    for (int ks = 0; ks < 4; ++ks) {
      bf16x8 af[4];
      #pragma unroll
      for (int im = 0; im < 4; ++im)
        af[im] = *(const bf16x8*)(ab + (im * 16 + col) * 128 + ((ks * 32 + q * 8) ^ swzR));
      #pragma unroll
      for (int im = 0; im < 4; ++im) {
        acc[im][0] = __builtin_amdgcn_mfma_f32_16x16x32_bf16(af[im], wf[ks],     acc[im][0], 0, 0, 0);
        acc[im][1] = __builtin_amdgcn_mfma_f32_16x16x32_bf16(af[im], wf[4 + ks], acc[im][1], 0, 0, 0);
      }
    }
    __builtin_amdgcn_s_setprio(0);
    if (kc < 7) {
      pack_to((kc & 1) ? A0v : A1v);         // feat wait: only fast weight loads ahead in queue
      wf_issue(kc + 1);                      // issued on a clean queue; ready after barrier
    }
    __syncthreads();
  }

  // epilogue L1 -> h1 (stride 256, swizzled, overlaps dead A dbuf)
  #pragma unroll
  for (int jj = 0; jj < 2; ++jj) {
    int n = (w + 8 * jj) * 16 + col;
    float bias = b1[t * NH1 + n];
    #pragma unroll
    for (int im = 0; im < 4; ++im)
      #pragma unroll
      for (int r = 0; r < 4; ++r) {
        int row = im * 16 + q * 4 + r;
        h1s[row * 256 + (n ^ ((row & 7) << 3))] = (__bf16)celu_f(acc[im][jj][r] + bias);
      }
  }
  __syncthreads();

  // ---- Layer 2: h2[64,192] = celu(h1 x W2 + b2), K=256, 12 n-tiles
  f32x4 acc2[4][2];
  #pragma unroll
  for (int a = 0; a < 4; ++a)
    #pragma unroll
    for (int b = 0; b < 2; ++b) acc2[a][b] = (f32x4){0.f, 0.f, 0.f, 0.f};
  const unsigned short* w2p0 = w2f + (size_t)t * 12 * 8 * 512 + (size_t)w * 8 * 512 + lx8;
  const unsigned short* w2p1 = w2p0 + 8 * 8 * 512;   // j = w+8, valid iff w < 4
  __builtin_amdgcn_s_setprio(1);
  #pragma unroll
  for (int ks = 0; ks < 8; ++ks) {
    bf16x8 af[4];
    #pragma unroll
    for (int im = 0; im < 4; ++im)
      af[im] = *(const bf16x8*)(h1s + (im * 16 + col) * 256 + ((ks * 32 + q * 8) ^ swzR));
    bf16x8 bf0 = *(const bf16x8*)(w2p0 + (size_t)ks * 512);
    #pragma unroll
    for (int im = 0; im < 4; ++im)
      acc2[im][0] = __builtin_amdgcn_mfma_f32_16x16x32_bf16(af[im], bf0, acc2[im][0], 0, 0, 0);
    if (w < 4) {
      bf16x8 bf1 = *(const bf16x8*)(w2p1 + (size_t)ks * 512);
      #pragma unroll
      for (int im = 0; im < 4; ++im)
        acc2[im][1] = __builtin_amdgcn_mfma_f32_16x16x32_bf16(af[im], bf1, acc2[im][1], 0, 0, 0);
    }
  }
  __builtin_amdgcn_s_setprio(0);
  #pragma unroll
  for (int jj = 0; jj < 2; ++jj) {
    int j = w + 8 * jj;
    if (j < 12) {
      int n = j * 16 + col;
      float bias = b2[t * NH2 + n];
      #pragma unroll
      for (int im = 0; im < 4; ++im)
        #pragma unroll
        for (int r = 0; r < 4; ++r) {
          int row = im * 16 + q * 4 + r;
          h2s[row * 192 + (n ^ ((row & 7) << 3))] = (__bf16)celu_f(acc2[im][jj][r] + bias);
        }
    }
  }
  __syncthreads();

  // ---- Layer 3: h3[64,160] = celu(h2 x W3 + b3), K=192, 10 n-tiles
  f32x4 acc3[4][2];
  #pragma unroll
  for (int a = 0; a < 4; ++a)
    #pragma unroll
    for (int b = 0; b < 2; ++b) acc3[a][b] = (f32x4){0.f, 0.f, 0.f, 0.f};
  const unsigned short* w3p0 = w3f + (size_t)t * 10 * 6 * 512 + (size_t)w * 6 * 512 + lx8;
  const unsigned short* w3p1 = w3p0 + 8 * 6 * 512;   // j = w+8, valid iff w < 2
  __builtin_amdgcn_s_setprio(1);
  #pragma unroll
  for (int ks = 0; ks < 6; ++ks) {
    bf16x8 af[4];
    #pragma unroll
    for (int im = 0; im < 4; ++im)
      af[im] = *(const bf16x8*)(h2s + (im * 16 + col) * 192 + ((ks * 32 + q * 8) ^ swzR));
    bf16x8 bf0 = *(const bf16x8*)(w3p0 + (size_t)ks * 512);
    #pragma unroll
    for (int im = 0; im < 4; ++im)
      acc3[im][0] = __builtin_amdgcn_mfma_f32_16x16x32_bf16(af[im], bf0, acc3[im][0], 0, 0, 0);
    if (w < 2) {
      bf16x8 bf1 = *(const bf16x8*)(w3p1 + (size_t)ks * 512);
      #pragma unroll
      for (int im = 0; im < 4; ++im)
        acc3[im][1] = __builtin_amdgcn_mfma_f32_16x16x32_bf16(af[im], bf1, acc3[im][1], 0, 0, 0);
    }
  }
  __builtin_amdgcn_s_setprio(0);
  #pragma unroll
  for (int jj = 0; jj < 2; ++jj) {
    int j = w + 8 * jj;
    if (j < 10) {
      int n = j * 16 + col;
      float bias = b3[t * NH3 + n];
      #pragma unroll
      for (int im = 0; im < 4; ++im)
        #pragma unroll
        for (int r = 0; r < 4; ++r) {
          int row = im * 16 + q * 4 + r;
          h3s[row * 192 + (n ^ ((row & 7) << 3))] = (__bf16)celu_f(acc3[im][jj][r] + bias);
        }
    }
  }
  __syncthreads();

  // ---- Layer 4: v = h3 . W4[t] + b4[t]; atomicAdd into molecule
  {
    int a = tid >> 3, p = tid & 7;
    float v = 0.f;
    if (a < rows) {
      const float* wp = W4 + t * NH3;
      int aswz = (a & 7) << 3;
      #pragma unroll
      for (int c0 = 0; c0 < 3; ++c0) {
        int c = p + 8 * c0;   // 20 chunks of 8 elems
        if (c < 20) {
          bf16x8 hv = *(const bf16x8*)(h3s + a * 192 + ((c * 8) ^ aswz));
          #pragma unroll
          for (int j = 0; j < 8; ++j) v += (float)hv[j] * wp[c * 8 + j];
        }
      }
    }
    v += __shfl_xor(v, 1);
    v += __shfl_xor(v, 2);
    v += __shfl_xor(v, 4);
    if (p == 0 && a < rows) {
      int g = lgid[a];
      atomicAdd(&out[batch[g]], v + b4[t]);
    }
  }
}

// ---------------- launch ----------------
extern "C" void kernel_launch(void* const* d_in, const int* in_sizes, int n_in,
                              void* d_out, int out_size, void* d_ws, size_t ws_size,
                              hipStream_t stream) {
  const int*   z    = (const int*)d_in[0];
  const float* feat = (const float*)d_in[1];
  const int*   bat  = (const int*)d_in[2];
  const float* W1 = (const float*)d_in[4];
  const float* b1 = (const float*)d_in[5];
  const float* W2 = (const float*)d_in[6];
  const float* b2 = (const float*)d_in[7];
  const float* W3 = (const float*)d_in[8];
  const float* b3 = (const float*)d_in[9];
  const float* W4 = (const float*)d_in[10];
  const float* b4 = (const float*)d_in[11];
  const int n = in_sizes[0];

  unsigned char* ws = (unsigned char*)d_ws;
  unsigned short* w1f = (unsigned short*)(ws + W1F_OFF);
  unsigned short* w2f = (unsigned short*)(ws + W2F_OFF);
  unsigned short* w3f = (unsigned short*)(ws + W3F_OFF);
  int* meta = (int*)(ws + META_OFF);
  int* counts    = meta;
  int* cursors   = meta + 24;
  int* sorted    = (int*)(ws + SORT_OFF);

  hipMemsetAsync(meta, 0, 128, stream);
  hipMemsetAsync(d_out, 0, (size_t)out_size * sizeof(float), stream);

  int nb = (n + 255) / 256;
  prep_and_hist<<<425 + nb, 256, 0, stream>>>(W1, W2, W3, w1f, w2f, w3f, z, n, counts);
  scatter_atoms<<<nb, 256, 0, stream>>>(z, n, counts, cursors, sorted);
  int max_tiles = n / MT + 6;
  fcnn_main<<<max_tiles, 512, 0, stream>>>(feat, bat, w1f, w2f, w3f, W4,
                                           b1, b2, b3, b4,
                                           counts, sorted,
                                           (float*)d_out);
  (void)n_in; (void)ws_size;
}